// Round 5
// baseline (536.562 us; speedup 1.0000x reference)
//
#include <hip/hip_runtime.h>

#define EMBED 64
#define BSHIFT 9
#define BROWS 512      // rows per coarse bucket
#define NGROUPS 256    // passA/passB blocks (private write fronts)
#define MAXNB 512      // max buckets supported by LDS arrays (nb=293 here)
#define SCAN_THREADS 256
#define SCAN_ITEMS 16
#define SCAN_TILE (SCAN_THREADS * SCAN_ITEMS)  // 4096

typedef unsigned short ushort_t;

__device__ __forceinline__ ushort_t f2bf(float f) {  // RTNE
    unsigned u = __float_as_uint(f);
    return (ushort_t)((u + 0x7FFFu + ((u >> 16) & 1u)) >> 16);
}
__device__ __forceinline__ float bf2f(ushort_t b) {
    return __uint_as_float(((unsigned)b) << 16);
}

// Generic per-tile exclusive scan: in -> out (tile-local) + tile sums.
__global__ void scan_tiles(const int* __restrict__ in, int* __restrict__ out,
                           int* __restrict__ tile_sums, int n) {
    __shared__ int sh[SCAN_THREADS];
    int t = threadIdx.x;
    int base = blockIdx.x * SCAN_TILE + t * SCAN_ITEMS;
    int vals[SCAN_ITEMS];
    int sum = 0;
#pragma unroll
    for (int k = 0; k < SCAN_ITEMS; ++k) {
        int idx = base + k;
        vals[k] = (idx < n) ? in[idx] : 0;
        sum += vals[k];
    }
    sh[t] = sum;
    __syncthreads();
    for (int off = 1; off < SCAN_THREADS; off <<= 1) {
        int v = (t >= off) ? sh[t - off] : 0;
        __syncthreads();
        sh[t] += v;
        __syncthreads();
    }
    int excl = sh[t] - sum;
    if (t == SCAN_THREADS - 1) tile_sums[blockIdx.x] = sh[t];
    int run = excl;
#pragma unroll
    for (int k = 0; k < SCAN_ITEMS; ++k) {
        int idx = base + k;
        if (idx < n) out[idx] = run;
        run += vals[k];
    }
}

__global__ void scan_bases(const int* __restrict__ tile_sums, int* __restrict__ tile_base,
                           int ntiles) {
    if (threadIdx.x == 0 && blockIdx.x == 0) {
        int run = 0;
        for (int i = 0; i < ntiles; ++i) { tile_base[i] = run; run += tile_sums[i]; }
        tile_base[ntiles] = run;
    }
}

__global__ void add_bases(int* __restrict__ arr, const int* __restrict__ tile_base,
                          int n, int ntiles) {
    int i = blockIdx.x * blockDim.x + threadIdx.x;
    if (i < n) arr[i] += tile_base[i / SCAN_TILE];
    if (i == 0) arr[n] = tile_base[ntiles];
}

// passA: per-block LDS histogram over coarse buckets -> cnt[bucket][block].
__global__ __launch_bounds__(256) void passA_hist(const int* __restrict__ row,
                                                  int* __restrict__ cnt,
                                                  int nnz, int nb, int epb) {
    __shared__ int hist[MAXNB];
    int g = blockIdx.x, t = threadIdx.x;
    for (int b = t; b < nb; b += 256) hist[b] = 0;
    __syncthreads();
    int i0 = g * epb, i1 = min(i0 + epb, nnz);
    for (int i = i0 + t; i < i1; i += 256) atomicAdd(&hist[row[i] >> BSHIFT], 1);
    __syncthreads();
    for (int b = t; b < nb; b += 256) cnt[b * NGROUPS + g] = hist[b];
}

// passB: deterministic scatter into block-private dense fronts (LDS cursors,
// no global atomics). 8 B/edge: (col) + (row). vals recomputed later from dinv.
__global__ __launch_bounds__(256) void passB_scatter(const int* __restrict__ row,
                                                     const int* __restrict__ col,
                                                     const int* __restrict__ cbase,
                                                     int* __restrict__ tcol,
                                                     int* __restrict__ trow,
                                                     int nnz, int nb, int epb) {
    __shared__ int lcur[MAXNB];
    int g = blockIdx.x, t = threadIdx.x;
    for (int b = t; b < nb; b += 256) lcur[b] = cbase[b * NGROUPS + g];
    __syncthreads();
    int i0 = g * epb, i1 = min(i0 + epb, nnz);
    for (int i = i0 + t; i < i1; i += 256) {
        int r = row[i];
        int slot = atomicAdd(&lcur[r >> BSHIFT], 1);
        tcol[slot] = col[i];
        trow[slot] = r;
    }
}

// deg via LDS-only atomics over the bucket-grouped trow stream.
__global__ __launch_bounds__(256) void deg_from_bins(const int* __restrict__ cbase,
                                                     const int* __restrict__ trow,
                                                     int* __restrict__ deg,
                                                     int n_nodes) {
    __shared__ int hist[BROWS];
    int b = blockIdx.x, t = threadIdx.x;
    int r0 = b * BROWS;
    int r1 = min(r0 + BROWS, n_nodes);
    for (int r = t; r < BROWS; r += 256) hist[r] = 0;
    __syncthreads();
    int es = cbase[b * NGROUPS];
    int ee = cbase[(b + 1) * NGROUPS];  // cbase[n2] == nnz
    for (int e = es + t; e < ee; e += 256) atomicAdd(&hist[trow[e] - r0], 1);
    __syncthreads();
    for (int r = r0 + t; r < r1; r += 256) deg[r] = hist[r - r0];
}

__global__ void make_dinv(const int* __restrict__ deg, float* __restrict__ dinv, int n) {
    int i = blockIdx.x * blockDim.x + threadIdx.x;
    if (i < n) dinv[i] = 1.0f / sqrtf((float)max(deg[i], 1));
}

// pass2: one block per bucket; LDS row-cursors; CSR col writes confined to the
// bucket's contiguous ~45 KB span (L2-resident).
__global__ __launch_bounds__(256) void pass2_place(const int* __restrict__ offs,
                                                   const int* __restrict__ trow,
                                                   const int* __restrict__ tcol,
                                                   int* __restrict__ ecol, int n_nodes) {
    __shared__ int lcur[BROWS];
    int b = blockIdx.x;
    int t = threadIdx.x;
    int r0 = b * BROWS;
    int r1 = min(r0 + BROWS, n_nodes);
    if (r0 >= n_nodes) return;
    for (int r = t; r < r1 - r0; r += 256) lcur[r] = offs[r0 + r];
    __syncthreads();
    int es = offs[r0];
    int ee = offs[r1];
    for (int e = es + t; e < ee; e += 256) {
        int r = trow[e];
        int c = tcol[e];
        int slot = atomicAdd(&lcur[r - r0], 1);
        ecol[slot] = c;
    }
}

// Build bf16 x0 = concat(user_emb, item_emb).
__global__ void concat_bf16(const float* __restrict__ ue, const float* __restrict__ ie,
                            ushort_t* __restrict__ x, int nu16, int tot16) {
    int stride = gridDim.x * blockDim.x;
    for (int i = blockIdx.x * blockDim.x + threadIdx.x; i < tot16; i += stride) {
        float4 v = (i < nu16) ? ((const float4*)ue)[i] : ((const float4*)ie)[i - nu16];
        ushort4 o;
        o.x = f2bf(v.x); o.y = f2bf(v.y); o.z = f2bf(v.z); o.w = f2bf(v.w);
        ((ushort4*)x)[i] = o;
    }
}

// One wave per node; 4 edge-groups x 16 lanes x 4 bf16; val = dinv[r]*dinv[c]
// recomputed (dinv is 600 KB -> L2-resident).
__global__ __launch_bounds__(256) void spmm_bf16(const int* __restrict__ offs,
                                                 const int* __restrict__ ecol,
                                                 const float* __restrict__ dinv,
                                                 const ushort_t* __restrict__ x,
                                                 ushort_t* __restrict__ y, int n_nodes) {
    int wave = blockIdx.x * (blockDim.x >> 6) + (threadIdx.x >> 6);
    if (wave >= n_nodes) return;
    int lane = threadIdx.x & 63;
    int g = lane >> 4;    // edge subgroup 0..3
    int l16 = lane & 15;  // dim-quad
    int start = offs[wave];
    int end = offs[wave + 1];
    float dr = dinv[wave];
    float a0 = 0.f, a1 = 0.f, a2 = 0.f, a3 = 0.f;
    for (int e = start + g; e < end; e += 4) {
        int c = ecol[e];
        float v = dr * dinv[c];
        ushort4 xv = *(const ushort4*)(x + (size_t)c * EMBED + l16 * 4);
        a0 += v * bf2f(xv.x);
        a1 += v * bf2f(xv.y);
        a2 += v * bf2f(xv.z);
        a3 += v * bf2f(xv.w);
    }
#pragma unroll
    for (int m = 16; m <= 32; m <<= 1) {
        a0 += __shfl_xor(a0, m);
        a1 += __shfl_xor(a1, m);
        a2 += __shfl_xor(a2, m);
        a3 += __shfl_xor(a3, m);
    }
    if (g == 0) {
        ushort4 o;
        o.x = f2bf(a0); o.y = f2bf(a1); o.z = f2bf(a2); o.w = f2bf(a3);
        *(ushort4*)(y + (size_t)wave * EMBED + l16 * 4) = o;
    }
}

// Layer-0 term, gathered EXACTLY from the f32 inputs (no bf16 rounding).
__global__ void gather_first(const float* __restrict__ ue, const float* __restrict__ ie,
                             const int* __restrict__ users, const int* __restrict__ pos,
                             const int* __restrict__ neg, float* __restrict__ out,
                             int batch) {
    int idx = blockIdx.x * blockDim.x + threadIdx.x;
    int total = 3 * batch * EMBED;
    if (idx >= total) return;
    int r = idx >> 6;
    int d = idx & 63;
    int which = r / batch;
    int b = r - which * batch;
    float v;
    if (which == 0) v = ue[(size_t)users[b] * EMBED + d];
    else v = ie[(size_t)((which == 1) ? pos[b] : neg[b]) * EMBED + d];
    out[idx] = 0.25f * v;
}

__global__ void gather_acc(const ushort_t* __restrict__ x, const int* __restrict__ users,
                           const int* __restrict__ pos, const int* __restrict__ neg,
                           float* __restrict__ out, int batch, int n_users) {
    int idx = blockIdx.x * blockDim.x + threadIdx.x;
    int total = 3 * batch * EMBED;
    if (idx >= total) return;
    int r = idx >> 6;
    int d = idx & 63;
    int which = r / batch;
    int b = r - which * batch;
    int node = (which == 0) ? users[b] : ((which == 1) ? (n_users + pos[b]) : (n_users + neg[b]));
    out[idx] += 0.25f * bf2f(x[(size_t)node * EMBED + d]);
}

extern "C" void kernel_launch(void* const* d_in, const int* in_sizes, int n_in,
                              void* d_out, int out_size, void* d_ws, size_t ws_size,
                              hipStream_t stream) {
    const float* user_emb = (const float*)d_in[0];
    const float* item_emb = (const float*)d_in[1];
    const int* row = (const int*)d_in[2];
    const int* col = (const int*)d_in[3];
    const int* users = (const int*)d_in[5];
    const int* pos = (const int*)d_in[6];
    const int* neg = (const int*)d_in[7];
    float* out = (float*)d_out;

    int n_users = in_sizes[0] / EMBED;
    int n_items = in_sizes[1] / EMBED;
    int n_nodes = n_users + n_items;
    int nnz = in_sizes[2];
    int batch = in_sizes[5];
    int nb = (n_nodes + BROWS - 1) / BROWS;   // 293
    int n2 = nb * NGROUPS;                    // 75008
    int epb = (nnz + NGROUPS - 1) / NGROUPS;  // 12500

    char* p = (char*)d_ws;
    auto alloc = [&](size_t bytes) -> void* {
        void* r = (void*)p;
        p += (bytes + 255) & ~(size_t)255;
        return r;
    };
    int ntiles1 = (n_nodes + SCAN_TILE - 1) / SCAN_TILE;
    int ntiles2 = (n2 + SCAN_TILE - 1) / SCAN_TILE;
    int ntiles_max = ntiles1 > ntiles2 ? ntiles1 : ntiles2;
    int* deg = (int*)alloc(sizeof(int) * (size_t)n_nodes);
    int* offs = (int*)alloc(sizeof(int) * (size_t)(n_nodes + 1));
    float* dinv = (float*)alloc(sizeof(float) * (size_t)n_nodes);
    int* cnt = (int*)alloc(sizeof(int) * (size_t)n2);
    int* cbase = (int*)alloc(sizeof(int) * (size_t)(n2 + 1));
    int* tile_sums = (int*)alloc(sizeof(int) * (size_t)ntiles_max);
    int* tile_base = (int*)alloc(sizeof(int) * (size_t)(ntiles_max + 1));
    int* ecol = (int*)alloc(sizeof(int) * (size_t)nnz);
    ushort_t* bufA = (ushort_t*)alloc(sizeof(ushort_t) * (size_t)n_nodes * EMBED);
    ushort_t* bufB = (ushort_t*)alloc(sizeof(ushort_t) * (size_t)n_nodes * EMBED);
    if ((size_t)(p - (char*)d_ws) > ws_size) return;  // workspace too small: bail visibly
    // tcol (12.8MB) aliases bufA (19.2MB); trow aliases bufB. Both consumed by
    // pass2 before concat/spmm write bufA/bufB.
    int* tcol = (int*)bufA;
    int* trow = (int*)bufB;

    passA_hist<<<NGROUPS, 256, 0, stream>>>(row, cnt, nnz, nb, epb);
    scan_tiles<<<ntiles2, SCAN_THREADS, 0, stream>>>(cnt, cbase, tile_sums, n2);
    scan_bases<<<1, 64, 0, stream>>>(tile_sums, tile_base, ntiles2);
    add_bases<<<(n2 + 255) / 256, 256, 0, stream>>>(cbase, tile_base, n2, ntiles2);
    passB_scatter<<<NGROUPS, 256, 0, stream>>>(row, col, cbase, tcol, trow, nnz, nb, epb);

    deg_from_bins<<<nb, 256, 0, stream>>>(cbase, trow, deg, n_nodes);
    make_dinv<<<(n_nodes + 255) / 256, 256, 0, stream>>>(deg, dinv, n_nodes);
    scan_tiles<<<ntiles1, SCAN_THREADS, 0, stream>>>(deg, offs, tile_sums, n_nodes);
    scan_bases<<<1, 64, 0, stream>>>(tile_sums, tile_base, ntiles1);
    add_bases<<<(n_nodes + 255) / 256, 256, 0, stream>>>(offs, tile_base, n_nodes, ntiles1);
    pass2_place<<<nb, 256, 0, stream>>>(offs, trow, tcol, ecol, n_nodes);

    int nu16 = n_users * EMBED / 4;
    int tot16 = n_nodes * EMBED / 4;
    concat_bf16<<<2048, 256, 0, stream>>>(user_emb, item_emb, bufA, nu16, tot16);

    int gblocks = (3 * batch * EMBED + 255) / 256;
    int spmm_blocks = (n_nodes + 3) / 4;

    gather_first<<<gblocks, 256, 0, stream>>>(user_emb, item_emb, users, pos, neg, out, batch);
    spmm_bf16<<<spmm_blocks, 256, 0, stream>>>(offs, ecol, dinv, bufA, bufB, n_nodes);
    gather_acc<<<gblocks, 256, 0, stream>>>(bufB, users, pos, neg, out, batch, n_users);
    spmm_bf16<<<spmm_blocks, 256, 0, stream>>>(offs, ecol, dinv, bufB, bufA, n_nodes);
    gather_acc<<<gblocks, 256, 0, stream>>>(bufA, users, pos, neg, out, batch, n_users);
    spmm_bf16<<<spmm_blocks, 256, 0, stream>>>(offs, ecol, dinv, bufA, bufB, n_nodes);
    gather_acc<<<gblocks, 256, 0, stream>>>(bufB, users, pos, neg, out, batch, n_users);
}

// Round 6
// 357.437 us; speedup vs baseline: 1.5011x; 1.5011x over previous
//
#include <hip/hip_runtime.h>

#define EMBED 64
#define BSHIFT 9
#define BROWS 512      // rows per coarse bucket
#define NGROUPS 256    // passA/passB blocks (private write fronts)
#define MAXNB 512      // max buckets supported by LDS arrays (nb=293 here)
#define SCAN_THREADS 256
#define SCAN_ITEMS 16
#define SCAN_TILE (SCAN_THREADS * SCAN_ITEMS)  // 4096

typedef unsigned short ushort_t;

__device__ __forceinline__ ushort_t f2bf(float f) {  // RTNE
    unsigned u = __float_as_uint(f);
    return (ushort_t)((u + 0x7FFFu + ((u >> 16) & 1u)) >> 16);
}
__device__ __forceinline__ float bf2f(ushort_t b) {
    return __uint_as_float(((unsigned)b) << 16);
}

// Generic per-tile exclusive scan: in -> out (tile-local) + tile sums.
__global__ void scan_tiles(const int* __restrict__ in, int* __restrict__ out,
                           int* __restrict__ tile_sums, int n) {
    __shared__ int sh[SCAN_THREADS];
    int t = threadIdx.x;
    int base = blockIdx.x * SCAN_TILE + t * SCAN_ITEMS;
    int vals[SCAN_ITEMS];
    int sum = 0;
#pragma unroll
    for (int k = 0; k < SCAN_ITEMS; ++k) {
        int idx = base + k;
        vals[k] = (idx < n) ? in[idx] : 0;
        sum += vals[k];
    }
    sh[t] = sum;
    __syncthreads();
    for (int off = 1; off < SCAN_THREADS; off <<= 1) {
        int v = (t >= off) ? sh[t - off] : 0;
        __syncthreads();
        sh[t] += v;
        __syncthreads();
    }
    int excl = sh[t] - sum;
    if (t == SCAN_THREADS - 1) tile_sums[blockIdx.x] = sh[t];
    int run = excl;
#pragma unroll
    for (int k = 0; k < SCAN_ITEMS; ++k) {
        int idx = base + k;
        if (idx < n) out[idx] = run;
        run += vals[k];
    }
}

__global__ void scan_bases(const int* __restrict__ tile_sums, int* __restrict__ tile_base,
                           int ntiles) {
    if (threadIdx.x == 0 && blockIdx.x == 0) {
        int run = 0;
        for (int i = 0; i < ntiles; ++i) { tile_base[i] = run; run += tile_sums[i]; }
        tile_base[ntiles] = run;
    }
}

__global__ void add_bases(int* __restrict__ arr, const int* __restrict__ tile_base,
                          int n, int ntiles) {
    int i = blockIdx.x * blockDim.x + threadIdx.x;
    if (i < n) arr[i] += tile_base[i / SCAN_TILE];
    if (i == 0) arr[n] = tile_base[ntiles];
}

// passA: per-block LDS histogram over coarse buckets -> cnt[bucket][block].
__global__ __launch_bounds__(256) void passA_hist(const int* __restrict__ row,
                                                  int* __restrict__ cnt,
                                                  int nnz, int nb, int epb) {
    __shared__ int hist[MAXNB];
    int g = blockIdx.x, t = threadIdx.x;
    for (int b = t; b < nb; b += 256) hist[b] = 0;
    __syncthreads();
    int i0 = g * epb, i1 = min(i0 + epb, nnz);
    for (int i = i0 + t; i < i1; i += 256) atomicAdd(&hist[row[i] >> BSHIFT], 1);
    __syncthreads();
    for (int b = t; b < nb; b += 256) cnt[b * NGROUPS + g] = hist[b];
}

// passB: deterministic scatter into block-private dense fronts (LDS cursors,
// no global atomics). 8 B/edge: (col) + (row).
__global__ __launch_bounds__(256) void passB_scatter(const int* __restrict__ row,
                                                     const int* __restrict__ col,
                                                     const int* __restrict__ cbase,
                                                     int* __restrict__ tcol,
                                                     int* __restrict__ trow,
                                                     int nnz, int nb, int epb) {
    __shared__ int lcur[MAXNB];
    int g = blockIdx.x, t = threadIdx.x;
    for (int b = t; b < nb; b += 256) lcur[b] = cbase[b * NGROUPS + g];
    __syncthreads();
    int i0 = g * epb, i1 = min(i0 + epb, nnz);
    for (int i = i0 + t; i < i1; i += 256) {
        int r = row[i];
        int slot = atomicAdd(&lcur[r >> BSHIFT], 1);
        tcol[slot] = col[i];
        trow[slot] = r;
    }
}

// deg via LDS-only atomics over the bucket-grouped trow stream.
__global__ __launch_bounds__(256) void deg_from_bins(const int* __restrict__ cbase,
                                                     const int* __restrict__ trow,
                                                     int* __restrict__ deg,
                                                     int n_nodes) {
    __shared__ int hist[BROWS];
    int b = blockIdx.x, t = threadIdx.x;
    int r0 = b * BROWS;
    int r1 = min(r0 + BROWS, n_nodes);
    for (int r = t; r < BROWS; r += 256) hist[r] = 0;
    __syncthreads();
    int es = cbase[b * NGROUPS];
    int ee = cbase[(b + 1) * NGROUPS];  // cbase[n2] == nnz
    for (int e = es + t; e < ee; e += 256) atomicAdd(&hist[trow[e] - r0], 1);
    __syncthreads();
    for (int r = r0 + t; r < r1; r += 256) deg[r] = hist[r - r0];
}

__global__ void make_dinv(const int* __restrict__ deg, float* __restrict__ dinv, int n) {
    int i = blockIdx.x * blockDim.x + threadIdx.x;
    if (i < n) dinv[i] = 1.0f / sqrtf((float)max(deg[i], 1));
}

// pass2: one block per bucket; LDS row-cursors; CSR col writes confined to the
// bucket's contiguous ~45 KB span (L2-resident).
__global__ __launch_bounds__(256) void pass2_place(const int* __restrict__ offs,
                                                   const int* __restrict__ trow,
                                                   const int* __restrict__ tcol,
                                                   int* __restrict__ ecol, int n_nodes) {
    __shared__ int lcur[BROWS];
    int b = blockIdx.x;
    int t = threadIdx.x;
    int r0 = b * BROWS;
    int r1 = min(r0 + BROWS, n_nodes);
    if (r0 >= n_nodes) return;
    for (int r = t; r < r1 - r0; r += 256) lcur[r] = offs[r0 + r];
    __syncthreads();
    int es = offs[r0];
    int ee = offs[r1];
    for (int e = es + t; e < ee; e += 256) {
        int r = trow[e];
        int c = tcol[e];
        int slot = atomicAdd(&lcur[r - r0], 1);
        ecol[slot] = c;
    }
}

// Build PRE-SCALED bf16 x0 = dinv .* concat(user_emb, item_emb).
__global__ void concat_bf16(const float* __restrict__ ue, const float* __restrict__ ie,
                            const float* __restrict__ dinv,
                            ushort_t* __restrict__ x, int nu16, int tot16) {
    int stride = gridDim.x * blockDim.x;
    for (int i = blockIdx.x * blockDim.x + threadIdx.x; i < tot16; i += stride) {
        float4 v = (i < nu16) ? ((const float4*)ue)[i] : ((const float4*)ie)[i - nu16];
        float d = dinv[i >> 4];  // 16 ushort4-groups per row
        ushort4 o;
        o.x = f2bf(d * v.x); o.y = f2bf(d * v.y); o.z = f2bf(d * v.z); o.w = f2bf(d * v.w);
        ((ushort4*)x)[i] = o;
    }
}

// SPMM on pre-scaled embeddings: acc_r = sum x~[c]; write x~_next = dinv[r]^2 * acc.
// 8 edge-groups x 8 lanes x uint4 (8 bf16). Edge ids prefetched per 64-chunk into
// registers; inner-loop c comes from register __shfl -> gather addresses never
// depend on in-flight loads; 8 edges in flight per vmem instruction.
__global__ __launch_bounds__(256) void spmm_bf16(const int* __restrict__ offs,
                                                 const int* __restrict__ ecol,
                                                 const float* __restrict__ dinv,
                                                 const ushort_t* __restrict__ x,
                                                 ushort_t* __restrict__ y, int n_nodes) {
    int wave = blockIdx.x * (blockDim.x >> 6) + (threadIdx.x >> 6);
    if (wave >= n_nodes) return;
    int lane = threadIdx.x & 63;
    int g = lane >> 3;   // edge subgroup 0..7
    int l8 = lane & 7;   // dim-oct
    int start = offs[wave];
    int end = offs[wave + 1];
    float a0 = 0.f, a1 = 0.f, a2 = 0.f, a3 = 0.f, a4 = 0.f, a5 = 0.f, a6 = 0.f, a7 = 0.f;
    for (int base = start; base < end; base += 64) {
        int m = end - base;
        if (m > 64) m = 64;
        int il = base + lane;
        int c_lane = (il < end) ? ecol[il] : 0;
        int nk = (m + 7) >> 3;
        for (int k = 0; k < nk; ++k) {
            int idx = (k << 3) + g;
            int c = __shfl(c_lane, idx);  // register broadcast, all lanes
            if (idx < m) {
                uint4 q = *(const uint4*)(x + (size_t)c * EMBED + l8 * 8);
                a0 += __uint_as_float(q.x << 16);
                a1 += __uint_as_float(q.x & 0xFFFF0000u);
                a2 += __uint_as_float(q.y << 16);
                a3 += __uint_as_float(q.y & 0xFFFF0000u);
                a4 += __uint_as_float(q.z << 16);
                a5 += __uint_as_float(q.z & 0xFFFF0000u);
                a6 += __uint_as_float(q.w << 16);
                a7 += __uint_as_float(q.w & 0xFFFF0000u);
            }
        }
    }
#pragma unroll
    for (int msk = 8; msk <= 32; msk <<= 1) {
        a0 += __shfl_xor(a0, msk);
        a1 += __shfl_xor(a1, msk);
        a2 += __shfl_xor(a2, msk);
        a3 += __shfl_xor(a3, msk);
        a4 += __shfl_xor(a4, msk);
        a5 += __shfl_xor(a5, msk);
        a6 += __shfl_xor(a6, msk);
        a7 += __shfl_xor(a7, msk);
    }
    if (g == 0) {
        float dr = dinv[wave];
        float s = dr * dr;
        uint4 o;
        o.x = (unsigned)f2bf(s * a0) | ((unsigned)f2bf(s * a1) << 16);
        o.y = (unsigned)f2bf(s * a2) | ((unsigned)f2bf(s * a3) << 16);
        o.z = (unsigned)f2bf(s * a4) | ((unsigned)f2bf(s * a5) << 16);
        o.w = (unsigned)f2bf(s * a6) | ((unsigned)f2bf(s * a7) << 16);
        *(uint4*)(y + (size_t)wave * EMBED + l8 * 8) = o;
    }
}

// Layer-0 term, gathered EXACTLY from the f32 inputs (no bf16 rounding).
__global__ void gather_first(const float* __restrict__ ue, const float* __restrict__ ie,
                             const int* __restrict__ users, const int* __restrict__ pos,
                             const int* __restrict__ neg, float* __restrict__ out,
                             int batch) {
    int idx = blockIdx.x * blockDim.x + threadIdx.x;
    int total = 3 * batch * EMBED;
    if (idx >= total) return;
    int r = idx >> 6;
    int d = idx & 63;
    int which = r / batch;
    int b = r - which * batch;
    float v;
    if (which == 0) v = ue[(size_t)users[b] * EMBED + d];
    else v = ie[(size_t)((which == 1) ? pos[b] : neg[b]) * EMBED + d];
    out[idx] = 0.25f * v;
}

// Un-scale the pre-scaled layer output: e = x~ * sqrt(deg).
__global__ void gather_acc(const ushort_t* __restrict__ x, const int* __restrict__ deg,
                           const int* __restrict__ users, const int* __restrict__ pos,
                           const int* __restrict__ neg, float* __restrict__ out,
                           int batch, int n_users) {
    int idx = blockIdx.x * blockDim.x + threadIdx.x;
    int total = 3 * batch * EMBED;
    if (idx >= total) return;
    int r = idx >> 6;
    int d = idx & 63;
    int which = r / batch;
    int b = r - which * batch;
    int node = (which == 0) ? users[b] : ((which == 1) ? (n_users + pos[b]) : (n_users + neg[b]));
    float sd = sqrtf((float)max(deg[node], 1));
    out[idx] += 0.25f * sd * bf2f(x[(size_t)node * EMBED + d]);
}

extern "C" void kernel_launch(void* const* d_in, const int* in_sizes, int n_in,
                              void* d_out, int out_size, void* d_ws, size_t ws_size,
                              hipStream_t stream) {
    const float* user_emb = (const float*)d_in[0];
    const float* item_emb = (const float*)d_in[1];
    const int* row = (const int*)d_in[2];
    const int* col = (const int*)d_in[3];
    const int* users = (const int*)d_in[5];
    const int* pos = (const int*)d_in[6];
    const int* neg = (const int*)d_in[7];
    float* out = (float*)d_out;

    int n_users = in_sizes[0] / EMBED;
    int n_items = in_sizes[1] / EMBED;
    int n_nodes = n_users + n_items;
    int nnz = in_sizes[2];
    int batch = in_sizes[5];
    int nb = (n_nodes + BROWS - 1) / BROWS;   // 293
    int n2 = nb * NGROUPS;                    // 75008
    int epb = (nnz + NGROUPS - 1) / NGROUPS;  // 12500

    char* p = (char*)d_ws;
    auto alloc = [&](size_t bytes) -> void* {
        void* r = (void*)p;
        p += (bytes + 255) & ~(size_t)255;
        return r;
    };
    int ntiles1 = (n_nodes + SCAN_TILE - 1) / SCAN_TILE;
    int ntiles2 = (n2 + SCAN_TILE - 1) / SCAN_TILE;
    int ntiles_max = ntiles1 > ntiles2 ? ntiles1 : ntiles2;
    int* deg = (int*)alloc(sizeof(int) * (size_t)n_nodes);
    int* offs = (int*)alloc(sizeof(int) * (size_t)(n_nodes + 1));
    float* dinv = (float*)alloc(sizeof(float) * (size_t)n_nodes);
    int* cnt = (int*)alloc(sizeof(int) * (size_t)n2);
    int* cbase = (int*)alloc(sizeof(int) * (size_t)(n2 + 1));
    int* tile_sums = (int*)alloc(sizeof(int) * (size_t)ntiles_max);
    int* tile_base = (int*)alloc(sizeof(int) * (size_t)(ntiles_max + 1));
    int* ecol = (int*)alloc(sizeof(int) * (size_t)nnz);
    ushort_t* bufA = (ushort_t*)alloc(sizeof(ushort_t) * (size_t)n_nodes * EMBED);
    ushort_t* bufB = (ushort_t*)alloc(sizeof(ushort_t) * (size_t)n_nodes * EMBED);
    if ((size_t)(p - (char*)d_ws) > ws_size) return;  // workspace too small: bail visibly
    // tcol (12.8MB) aliases bufA (19.2MB); trow aliases bufB. Both consumed by
    // pass2 before concat/spmm write bufA/bufB.
    int* tcol = (int*)bufA;
    int* trow = (int*)bufB;

    passA_hist<<<NGROUPS, 256, 0, stream>>>(row, cnt, nnz, nb, epb);
    scan_tiles<<<ntiles2, SCAN_THREADS, 0, stream>>>(cnt, cbase, tile_sums, n2);
    scan_bases<<<1, 64, 0, stream>>>(tile_sums, tile_base, ntiles2);
    add_bases<<<(n2 + 255) / 256, 256, 0, stream>>>(cbase, tile_base, n2, ntiles2);
    passB_scatter<<<NGROUPS, 256, 0, stream>>>(row, col, cbase, tcol, trow, nnz, nb, epb);

    deg_from_bins<<<nb, 256, 0, stream>>>(cbase, trow, deg, n_nodes);
    make_dinv<<<(n_nodes + 255) / 256, 256, 0, stream>>>(deg, dinv, n_nodes);
    scan_tiles<<<ntiles1, SCAN_THREADS, 0, stream>>>(deg, offs, tile_sums, n_nodes);
    scan_bases<<<1, 64, 0, stream>>>(tile_sums, tile_base, ntiles1);
    add_bases<<<(n_nodes + 255) / 256, 256, 0, stream>>>(offs, tile_base, n_nodes, ntiles1);
    pass2_place<<<nb, 256, 0, stream>>>(offs, trow, tcol, ecol, n_nodes);

    int nu16 = n_users * EMBED / 4;
    int tot16 = n_nodes * EMBED / 4;
    concat_bf16<<<2048, 256, 0, stream>>>(user_emb, item_emb, dinv, bufA, nu16, tot16);

    int gblocks = (3 * batch * EMBED + 255) / 256;
    int spmm_blocks = (n_nodes + 3) / 4;

    gather_first<<<gblocks, 256, 0, stream>>>(user_emb, item_emb, users, pos, neg, out, batch);
    spmm_bf16<<<spmm_blocks, 256, 0, stream>>>(offs, ecol, dinv, bufA, bufB, n_nodes);
    gather_acc<<<gblocks, 256, 0, stream>>>(bufB, deg, users, pos, neg, out, batch, n_users);
    spmm_bf16<<<spmm_blocks, 256, 0, stream>>>(offs, ecol, dinv, bufB, bufA, n_nodes);
    gather_acc<<<gblocks, 256, 0, stream>>>(bufA, deg, users, pos, neg, out, batch, n_users);
    spmm_bf16<<<spmm_blocks, 256, 0, stream>>>(offs, ecol, dinv, bufA, bufB, n_nodes);
    gather_acc<<<gblocks, 256, 0, stream>>>(bufB, deg, users, pos, neg, out, batch, n_users);
}

// Round 7
// 351.290 us; speedup vs baseline: 1.5274x; 1.0175x over previous
//
#include <hip/hip_runtime.h>

#define EMBED 64
#define BSHIFT 9
#define BROWS 512      // rows per coarse bucket
#define NGROUPS 256    // passA/passB blocks (private write fronts)
#define MAXNB 512      // max buckets supported by LDS arrays (nb=293 here)
#define SCAN_THREADS 256
#define SCAN_ITEMS 16
#define SCAN_TILE (SCAN_THREADS * SCAN_ITEMS)  // 4096
// pack: (row & 511) << 20 | col   (col < 2^20; n_nodes = 150K fits)

typedef unsigned short ushort_t;

__device__ __forceinline__ ushort_t f2bf(float f) {  // RTNE
    unsigned u = __float_as_uint(f);
    return (ushort_t)((u + 0x7FFFu + ((u >> 16) & 1u)) >> 16);
}
__device__ __forceinline__ float bf2f(ushort_t b) {
    return __uint_as_float(((unsigned)b) << 16);
}

// Generic per-tile exclusive scan: in -> out (tile-local) + tile sums.
__global__ void scan_tiles(const int* __restrict__ in, int* __restrict__ out,
                           int* __restrict__ tile_sums, int n) {
    __shared__ int sh[SCAN_THREADS];
    int t = threadIdx.x;
    int base = blockIdx.x * SCAN_TILE + t * SCAN_ITEMS;
    int vals[SCAN_ITEMS];
    int sum = 0;
#pragma unroll
    for (int k = 0; k < SCAN_ITEMS; ++k) {
        int idx = base + k;
        vals[k] = (idx < n) ? in[idx] : 0;
        sum += vals[k];
    }
    sh[t] = sum;
    __syncthreads();
    for (int off = 1; off < SCAN_THREADS; off <<= 1) {
        int v = (t >= off) ? sh[t - off] : 0;
        __syncthreads();
        sh[t] += v;
        __syncthreads();
    }
    int excl = sh[t] - sum;
    if (t == SCAN_THREADS - 1) tile_sums[blockIdx.x] = sh[t];
    int run = excl;
#pragma unroll
    for (int k = 0; k < SCAN_ITEMS; ++k) {
        int idx = base + k;
        if (idx < n) out[idx] = run;
        run += vals[k];
    }
}

__global__ void scan_bases(const int* __restrict__ tile_sums, int* __restrict__ tile_base,
                           int ntiles) {
    if (threadIdx.x == 0 && blockIdx.x == 0) {
        int run = 0;
        for (int i = 0; i < ntiles; ++i) { tile_base[i] = run; run += tile_sums[i]; }
        tile_base[ntiles] = run;
    }
}

__global__ void add_bases(int* __restrict__ arr, const int* __restrict__ tile_base,
                          int n, int ntiles) {
    int i = blockIdx.x * blockDim.x + threadIdx.x;
    if (i < n) arr[i] += tile_base[i / SCAN_TILE];
    if (i == 0) arr[n] = tile_base[ntiles];
}

// passA: per-block LDS histogram over coarse buckets -> cnt[bucket][block].
__global__ __launch_bounds__(256) void passA_hist(const int* __restrict__ row,
                                                  int* __restrict__ cnt,
                                                  int nnz, int nb, int epb) {
    __shared__ int hist[MAXNB];
    int g = blockIdx.x, t = threadIdx.x;
    for (int b = t; b < nb; b += 256) hist[b] = 0;
    __syncthreads();
    int i0 = g * epb, i1 = min(i0 + epb, nnz);
    for (int i = i0 + t; i < i1; i += 256) atomicAdd(&hist[row[i] >> BSHIFT], 1);
    __syncthreads();
    for (int b = t; b < nb; b += 256) cnt[b * NGROUPS + g] = hist[b];
}

// passB: deterministic scatter into block-private dense fronts (LDS cursors,
// no global atomics). 4 B/edge: (rlocal<<20)|col.
__global__ __launch_bounds__(256) void passB_scatter(const int* __restrict__ row,
                                                     const int* __restrict__ col,
                                                     const int* __restrict__ cbase,
                                                     int* __restrict__ tpack,
                                                     int nnz, int nb, int epb) {
    __shared__ int lcur[MAXNB];
    int g = blockIdx.x, t = threadIdx.x;
    for (int b = t; b < nb; b += 256) lcur[b] = cbase[b * NGROUPS + g];
    __syncthreads();
    int i0 = g * epb, i1 = min(i0 + epb, nnz);
    for (int i = i0 + t; i < i1; i += 256) {
        int r = row[i];
        int slot = atomicAdd(&lcur[r >> BSHIFT], 1);
        tpack[slot] = ((r & (BROWS - 1)) << 20) | col[i];
    }
}

// deg via LDS-only atomics over the bucket-grouped packed stream.
__global__ __launch_bounds__(256) void deg_from_bins(const int* __restrict__ cbase,
                                                     const int* __restrict__ tpack,
                                                     int* __restrict__ deg,
                                                     int n_nodes) {
    __shared__ int hist[BROWS];
    int b = blockIdx.x, t = threadIdx.x;
    int r0 = b * BROWS;
    int r1 = min(r0 + BROWS, n_nodes);
    for (int r = t; r < BROWS; r += 256) hist[r] = 0;
    __syncthreads();
    int es = cbase[b * NGROUPS];
    int ee = cbase[(b + 1) * NGROUPS];  // cbase[n2] == nnz
    for (int e = es + t; e < ee; e += 256) atomicAdd(&hist[((unsigned)tpack[e]) >> 20], 1);
    __syncthreads();
    for (int r = r0 + t; r < r1; r += 256) deg[r] = hist[r - r0];
}

__global__ void make_dinv(const int* __restrict__ deg, float* __restrict__ dinv, int n) {
    int i = blockIdx.x * blockDim.x + threadIdx.x;
    if (i < n) dinv[i] = 1.0f / sqrtf((float)max(deg[i], 1));
}

// pass2: one block per bucket; LDS row-cursors; CSR col writes confined to the
// bucket's contiguous ~45 KB span (L2-resident).
__global__ __launch_bounds__(256) void pass2_place(const int* __restrict__ offs,
                                                   const int* __restrict__ tpack,
                                                   int* __restrict__ ecol, int n_nodes) {
    __shared__ int lcur[BROWS];
    int b = blockIdx.x;
    int t = threadIdx.x;
    int r0 = b * BROWS;
    int r1 = min(r0 + BROWS, n_nodes);
    if (r0 >= n_nodes) return;
    for (int r = t; r < r1 - r0; r += 256) lcur[r] = offs[r0 + r];
    __syncthreads();
    int es = offs[r0];
    int ee = offs[r1];
    for (int e = es + t; e < ee; e += 256) {
        int pk = tpack[e];
        int slot = atomicAdd(&lcur[((unsigned)pk) >> 20], 1);
        ecol[slot] = pk & 0xFFFFF;
    }
}

// Build PRE-SCALED bf16 x0 = dinv .* concat(user_emb, item_emb); also zero the
// pad row (index n_nodes) of BOTH buffers so invalid gather lanes add 0.
__global__ void concat_bf16(const float* __restrict__ ue, const float* __restrict__ ie,
                            const float* __restrict__ dinv,
                            ushort_t* __restrict__ xa, ushort_t* __restrict__ xb,
                            int nu16, int tot16, int n_nodes) {
    int i0 = blockIdx.x * blockDim.x + threadIdx.x;
    if (blockIdx.x == 0 && threadIdx.x < 32) {
        ushort4 z = {0, 0, 0, 0};
        ushort_t* tgt = (threadIdx.x < 16) ? xa : xb;
        ((ushort4*)(tgt + (size_t)n_nodes * EMBED))[threadIdx.x & 15] = z;
    }
    int stride = gridDim.x * blockDim.x;
    for (int i = i0; i < tot16; i += stride) {
        float4 v = (i < nu16) ? ((const float4*)ue)[i] : ((const float4*)ie)[i - nu16];
        float d = dinv[i >> 4];  // 16 ushort4-groups per row
        ushort4 o;
        o.x = f2bf(d * v.x); o.y = f2bf(d * v.y); o.z = f2bf(d * v.z); o.w = f2bf(d * v.w);
        ((ushort4*)xa)[i] = o;
    }
}

// SPMM on pre-scaled embeddings: acc_r = sum x~[c]; write x~_next = dinv[r]^2 * acc.
// 8 edge-groups x 8 lanes x uint4 (8 bf16). Edge ids prefetched per 64-chunk into
// registers; branchless inner loop (invalid lanes gather the zero pad row);
// unroll-2 keeps >=2 gathers in flight.
__global__ __launch_bounds__(256) void spmm_bf16(const int* __restrict__ offs,
                                                 const int* __restrict__ ecol,
                                                 const float* __restrict__ dinv,
                                                 const ushort_t* __restrict__ x,
                                                 ushort_t* __restrict__ y, int n_nodes) {
    int wave = blockIdx.x * (blockDim.x >> 6) + (threadIdx.x >> 6);
    if (wave >= n_nodes) return;
    int lane = threadIdx.x & 63;
    int g = lane >> 3;   // edge subgroup 0..7
    int l8 = lane & 7;   // dim-oct
    int start = offs[wave];
    int end = offs[wave + 1];
    float a0 = 0.f, a1 = 0.f, a2 = 0.f, a3 = 0.f, a4 = 0.f, a5 = 0.f, a6 = 0.f, a7 = 0.f;
    for (int base = start; base < end; base += 64) {
        int m = end - base;
        if (m > 64) m = 64;
        int il = base + lane;
        int c_lane = (il < end) ? ecol[il] : n_nodes;  // pad lanes -> zero row
        int nk = (m + 7) >> 3;
#pragma unroll 2
        for (int k = 0; k < nk; ++k) {
            int c = __shfl(c_lane, (k << 3) + g);  // register broadcast
            uint4 q = *(const uint4*)(x + ((size_t)c << 6) + l8 * 8);
            a0 += __uint_as_float(q.x << 16);
            a1 += __uint_as_float(q.x & 0xFFFF0000u);
            a2 += __uint_as_float(q.y << 16);
            a3 += __uint_as_float(q.y & 0xFFFF0000u);
            a4 += __uint_as_float(q.z << 16);
            a5 += __uint_as_float(q.z & 0xFFFF0000u);
            a6 += __uint_as_float(q.w << 16);
            a7 += __uint_as_float(q.w & 0xFFFF0000u);
        }
    }
#pragma unroll
    for (int msk = 8; msk <= 32; msk <<= 1) {
        a0 += __shfl_xor(a0, msk);
        a1 += __shfl_xor(a1, msk);
        a2 += __shfl_xor(a2, msk);
        a3 += __shfl_xor(a3, msk);
        a4 += __shfl_xor(a4, msk);
        a5 += __shfl_xor(a5, msk);
        a6 += __shfl_xor(a6, msk);
        a7 += __shfl_xor(a7, msk);
    }
    if (g == 0) {
        float dr = dinv[wave];
        float s = dr * dr;
        uint4 o;
        o.x = (unsigned)f2bf(s * a0) | ((unsigned)f2bf(s * a1) << 16);
        o.y = (unsigned)f2bf(s * a2) | ((unsigned)f2bf(s * a3) << 16);
        o.z = (unsigned)f2bf(s * a4) | ((unsigned)f2bf(s * a5) << 16);
        o.w = (unsigned)f2bf(s * a6) | ((unsigned)f2bf(s * a7) << 16);
        *(uint4*)(y + (size_t)wave * EMBED + l8 * 8) = o;
    }
}

// Layer-0 term, gathered EXACTLY from the f32 inputs (no bf16 rounding).
__global__ void gather_first(const float* __restrict__ ue, const float* __restrict__ ie,
                             const int* __restrict__ users, const int* __restrict__ pos,
                             const int* __restrict__ neg, float* __restrict__ out,
                             int batch) {
    int idx = blockIdx.x * blockDim.x + threadIdx.x;
    int total = 3 * batch * EMBED;
    if (idx >= total) return;
    int r = idx >> 6;
    int d = idx & 63;
    int which = r / batch;
    int b = r - which * batch;
    float v;
    if (which == 0) v = ue[(size_t)users[b] * EMBED + d];
    else v = ie[(size_t)((which == 1) ? pos[b] : neg[b]) * EMBED + d];
    out[idx] = 0.25f * v;
}

// Un-scale the pre-scaled layer output: e = x~ * sqrt(deg).
__global__ void gather_acc(const ushort_t* __restrict__ x, const int* __restrict__ deg,
                           const int* __restrict__ users, const int* __restrict__ pos,
                           const int* __restrict__ neg, float* __restrict__ out,
                           int batch, int n_users) {
    int idx = blockIdx.x * blockDim.x + threadIdx.x;
    int total = 3 * batch * EMBED;
    if (idx >= total) return;
    int r = idx >> 6;
    int d = idx & 63;
    int which = r / batch;
    int b = r - which * batch;
    int node = (which == 0) ? users[b] : ((which == 1) ? (n_users + pos[b]) : (n_users + neg[b]));
    float sd = sqrtf((float)max(deg[node], 1));
    out[idx] += 0.25f * sd * bf2f(x[(size_t)node * EMBED + d]);
}

extern "C" void kernel_launch(void* const* d_in, const int* in_sizes, int n_in,
                              void* d_out, int out_size, void* d_ws, size_t ws_size,
                              hipStream_t stream) {
    const float* user_emb = (const float*)d_in[0];
    const float* item_emb = (const float*)d_in[1];
    const int* row = (const int*)d_in[2];
    const int* col = (const int*)d_in[3];
    const int* users = (const int*)d_in[5];
    const int* pos = (const int*)d_in[6];
    const int* neg = (const int*)d_in[7];
    float* out = (float*)d_out;

    int n_users = in_sizes[0] / EMBED;
    int n_items = in_sizes[1] / EMBED;
    int n_nodes = n_users + n_items;
    int nnz = in_sizes[2];
    int batch = in_sizes[5];
    int nb = (n_nodes + BROWS - 1) / BROWS;   // 293
    int n2 = nb * NGROUPS;                    // 75008
    int epb = (nnz + NGROUPS - 1) / NGROUPS;  // 12500

    char* p = (char*)d_ws;
    auto alloc = [&](size_t bytes) -> void* {
        void* r = (void*)p;
        p += (bytes + 255) & ~(size_t)255;
        return r;
    };
    int ntiles1 = (n_nodes + SCAN_TILE - 1) / SCAN_TILE;
    int ntiles2 = (n2 + SCAN_TILE - 1) / SCAN_TILE;
    int ntiles_max = ntiles1 > ntiles2 ? ntiles1 : ntiles2;
    int* deg = (int*)alloc(sizeof(int) * (size_t)n_nodes);
    int* offs = (int*)alloc(sizeof(int) * (size_t)(n_nodes + 1));
    float* dinv = (float*)alloc(sizeof(float) * (size_t)n_nodes);
    int* cnt = (int*)alloc(sizeof(int) * (size_t)n2);
    int* cbase = (int*)alloc(sizeof(int) * (size_t)(n2 + 1));
    int* tile_sums = (int*)alloc(sizeof(int) * (size_t)ntiles_max);
    int* tile_base = (int*)alloc(sizeof(int) * (size_t)(ntiles_max + 1));
    int* ecol = (int*)alloc(sizeof(int) * (size_t)nnz);
    ushort_t* bufA = (ushort_t*)alloc(sizeof(ushort_t) * (size_t)(n_nodes + 1) * EMBED);
    ushort_t* bufB = (ushort_t*)alloc(sizeof(ushort_t) * (size_t)(n_nodes + 1) * EMBED);
    if ((size_t)(p - (char*)d_ws) > ws_size) return;  // workspace too small: bail visibly
    // tpack (12.8MB) aliases bufA (19.2MB); consumed by pass2 before concat/spmm
    // write bufA.
    int* tpack = (int*)bufA;

    passA_hist<<<NGROUPS, 256, 0, stream>>>(row, cnt, nnz, nb, epb);
    scan_tiles<<<ntiles2, SCAN_THREADS, 0, stream>>>(cnt, cbase, tile_sums, n2);
    scan_bases<<<1, 64, 0, stream>>>(tile_sums, tile_base, ntiles2);
    add_bases<<<(n2 + 255) / 256, 256, 0, stream>>>(cbase, tile_base, n2, ntiles2);
    passB_scatter<<<NGROUPS, 256, 0, stream>>>(row, col, cbase, tpack, nnz, nb, epb);

    deg_from_bins<<<nb, 256, 0, stream>>>(cbase, tpack, deg, n_nodes);
    make_dinv<<<(n_nodes + 255) / 256, 256, 0, stream>>>(deg, dinv, n_nodes);
    scan_tiles<<<ntiles1, SCAN_THREADS, 0, stream>>>(deg, offs, tile_sums, n_nodes);
    scan_bases<<<1, 64, 0, stream>>>(tile_sums, tile_base, ntiles1);
    add_bases<<<(n_nodes + 255) / 256, 256, 0, stream>>>(offs, tile_base, n_nodes, ntiles1);
    pass2_place<<<nb, 256, 0, stream>>>(offs, tpack, ecol, n_nodes);

    int nu16 = n_users * EMBED / 4;
    int tot16 = n_nodes * EMBED / 4;
    concat_bf16<<<2048, 256, 0, stream>>>(user_emb, item_emb, dinv, bufA, bufB, nu16, tot16,
                                          n_nodes);

    int gblocks = (3 * batch * EMBED + 255) / 256;
    int spmm_blocks = (n_nodes + 3) / 4;

    gather_first<<<gblocks, 256, 0, stream>>>(user_emb, item_emb, users, pos, neg, out, batch);
    spmm_bf16<<<spmm_blocks, 256, 0, stream>>>(offs, ecol, dinv, bufA, bufB, n_nodes);
    gather_acc<<<gblocks, 256, 0, stream>>>(bufB, deg, users, pos, neg, out, batch, n_users);
    spmm_bf16<<<spmm_blocks, 256, 0, stream>>>(offs, ecol, dinv, bufB, bufA, n_nodes);
    gather_acc<<<gblocks, 256, 0, stream>>>(bufA, deg, users, pos, neg, out, batch, n_users);
    spmm_bf16<<<spmm_blocks, 256, 0, stream>>>(offs, ecol, dinv, bufA, bufB, n_nodes);
    gather_acc<<<gblocks, 256, 0, stream>>>(bufB, deg, users, pos, neg, out, batch, n_users);
}

// Round 8
// 336.440 us; speedup vs baseline: 1.5948x; 1.0441x over previous
//
#include <hip/hip_runtime.h>

#define EMBED 64
#define BSHIFT 9
#define BROWS 512      // rows per coarse bucket
#define NGROUPS 256    // passA/passB blocks (private write fronts)
#define MAXNB 512      // max buckets supported by LDS arrays (nb=293 here)
#define SCAN_THREADS 256
#define SCAN_ITEMS 16
#define SCAN_TILE (SCAN_THREADS * SCAN_ITEMS)  // 4096
// pack: (row & 511) << 20 | col   (col < 2^20; n_nodes = 150K fits)

typedef unsigned short ushort_t;
typedef __attribute__((ext_vector_type(2))) float f32x2;

__device__ __forceinline__ ushort_t f2bf(float f) {  // RTNE
    unsigned u = __float_as_uint(f);
    return (ushort_t)((u + 0x7FFFu + ((u >> 16) & 1u)) >> 16);
}
__device__ __forceinline__ float bf2f(ushort_t b) {
    return __uint_as_float(((unsigned)b) << 16);
}

// Generic per-tile exclusive scan: in -> out (tile-local) + tile sums.
__global__ void scan_tiles(const int* __restrict__ in, int* __restrict__ out,
                           int* __restrict__ tile_sums, int n) {
    __shared__ int sh[SCAN_THREADS];
    int t = threadIdx.x;
    int base = blockIdx.x * SCAN_TILE + t * SCAN_ITEMS;
    int vals[SCAN_ITEMS];
    int sum = 0;
#pragma unroll
    for (int k = 0; k < SCAN_ITEMS; ++k) {
        int idx = base + k;
        vals[k] = (idx < n) ? in[idx] : 0;
        sum += vals[k];
    }
    sh[t] = sum;
    __syncthreads();
    for (int off = 1; off < SCAN_THREADS; off <<= 1) {
        int v = (t >= off) ? sh[t - off] : 0;
        __syncthreads();
        sh[t] += v;
        __syncthreads();
    }
    int excl = sh[t] - sum;
    if (t == SCAN_THREADS - 1) tile_sums[blockIdx.x] = sh[t];
    int run = excl;
#pragma unroll
    for (int k = 0; k < SCAN_ITEMS; ++k) {
        int idx = base + k;
        if (idx < n) out[idx] = run;
        run += vals[k];
    }
}

// Folded scan_bases+add_bases: each thread re-sums the (<=19) tile sums.
__global__ void add_bases_f(int* __restrict__ arr, const int* __restrict__ tile_sums,
                            int n, int ntiles) {
    int i = blockIdx.x * blockDim.x + threadIdx.x;
    if (i >= n) {
        if (i == n) {
            int s = 0;
            for (int j = 0; j < ntiles; ++j) s += tile_sums[j];
            arr[n] = s;
        }
        return;
    }
    int myt = i / SCAN_TILE;
    int base = 0;
    for (int j = 0; j < myt; ++j) base += tile_sums[j];
    arr[i] += base;
}

// passA: per-block LDS histogram over coarse buckets -> cnt[bucket][block].
__global__ __launch_bounds__(256) void passA_hist(const int* __restrict__ row,
                                                  int* __restrict__ cnt,
                                                  int nnz, int nb, int epb) {
    __shared__ int hist[MAXNB];
    int g = blockIdx.x, t = threadIdx.x;
    for (int b = t; b < nb; b += 256) hist[b] = 0;
    __syncthreads();
    int i0 = g * epb, i1 = min(i0 + epb, nnz);
    for (int i = i0 + t; i < i1; i += 256) atomicAdd(&hist[row[i] >> BSHIFT], 1);
    __syncthreads();
    for (int b = t; b < nb; b += 256) cnt[b * NGROUPS + g] = hist[b];
}

// passB: deterministic scatter into block-private dense fronts (LDS cursors,
// no global atomics). 4 B/edge: (rlocal<<20)|col.
__global__ __launch_bounds__(256) void passB_scatter(const int* __restrict__ row,
                                                     const int* __restrict__ col,
                                                     const int* __restrict__ cbase,
                                                     int* __restrict__ tpack,
                                                     int nnz, int nb, int epb) {
    __shared__ int lcur[MAXNB];
    int g = blockIdx.x, t = threadIdx.x;
    for (int b = t; b < nb; b += 256) lcur[b] = cbase[b * NGROUPS + g];
    __syncthreads();
    int i0 = g * epb, i1 = min(i0 + epb, nnz);
    for (int i = i0 + t; i < i1; i += 256) {
        int r = row[i];
        int slot = atomicAdd(&lcur[r >> BSHIFT], 1);
        tpack[slot] = ((r & (BROWS - 1)) << 20) | col[i];
    }
}

// Fused: deg (LDS histogram over bucket-grouped tpack) + dinv + pre-scaled
// bf16 x0 rows for this bucket + zero pad rows (block 0).
__global__ __launch_bounds__(256) void deg_dinv_x0(const int* __restrict__ cbase,
                                                   const int* __restrict__ tpack,
                                                   const float* __restrict__ ue,
                                                   const float* __restrict__ ie,
                                                   int* __restrict__ deg,
                                                   float* __restrict__ dinv,
                                                   ushort_t* __restrict__ xa,
                                                   ushort_t* __restrict__ xb,
                                                   ushort_t* __restrict__ xc,
                                                   int n_nodes, int n_users) {
    __shared__ int hist[BROWS];
    __shared__ float sdinv[BROWS];
    int b = blockIdx.x, t = threadIdx.x;
    int r0 = b * BROWS;
    int r1 = min(r0 + BROWS, n_nodes);
    for (int r = t; r < BROWS; r += 256) hist[r] = 0;
    __syncthreads();
    int es = cbase[b * NGROUPS];
    int ee = cbase[(b + 1) * NGROUPS];  // cbase[n2] == nnz
    for (int e = es + t; e < ee; e += 256) atomicAdd(&hist[((unsigned)tpack[e]) >> 20], 1);
    __syncthreads();
    for (int r = t; r < r1 - r0; r += 256) {
        int d = hist[r];
        deg[r0 + r] = d;
        float di = 1.0f / sqrtf((float)max(d, 1));
        dinv[r0 + r] = di;
        sdinv[r] = di;
    }
    __syncthreads();
    int nq = (r1 - r0) * 16;  // ushort4 quads in this bucket
    for (int idx = t; idx < nq; idx += 256) {
        int rl = idx >> 4, q = idx & 15;
        int grow = r0 + rl;
        const float* src = (grow < n_users) ? (ue + (size_t)grow * EMBED)
                                            : (ie + (size_t)(grow - n_users) * EMBED);
        float4 v = ((const float4*)src)[q];
        float d = sdinv[rl];
        ushort4 o;
        o.x = f2bf(d * v.x); o.y = f2bf(d * v.y); o.z = f2bf(d * v.z); o.w = f2bf(d * v.w);
        ((ushort4*)(xa + (size_t)grow * EMBED))[q] = o;
    }
    if (b == 0 && t < 48) {  // zero the pad row (index n_nodes) of all 3 buffers
        ushort4 z = {0, 0, 0, 0};
        ushort_t* tgt = (t < 16) ? xa : ((t < 32) ? xb : xc);
        ((ushort4*)(tgt + (size_t)n_nodes * EMBED))[t & 15] = z;
    }
}

// pass2: one block per bucket; LDS row-cursors; CSR col writes confined to the
// bucket's contiguous ~45 KB span (L2-resident).
__global__ __launch_bounds__(256) void pass2_place(const int* __restrict__ offs,
                                                   const int* __restrict__ tpack,
                                                   int* __restrict__ ecol, int n_nodes) {
    __shared__ int lcur[BROWS];
    int b = blockIdx.x;
    int t = threadIdx.x;
    int r0 = b * BROWS;
    int r1 = min(r0 + BROWS, n_nodes);
    if (r0 >= n_nodes) return;
    for (int r = t; r < r1 - r0; r += 256) lcur[r] = offs[r0 + r];
    __syncthreads();
    int es = offs[r0];
    int ee = offs[r1];
    for (int e = es + t; e < ee; e += 256) {
        int pk = tpack[e];
        int slot = atomicAdd(&lcur[((unsigned)pk) >> 20], 1);
        ecol[slot] = pk & 0xFFFFF;
    }
}

// SPMM on pre-scaled embeddings: acc_r = sum x~[c]; write x~_next = dinv[r]^2 * acc.
// 8 edge-groups x 8 lanes x uint4 (8 bf16); f32x2 accumulators (v_pk_add_f32);
// branchless inner loop (pad lanes gather the zero row); unroll 4.
__global__ __launch_bounds__(256) void spmm_bf16(const int* __restrict__ offs,
                                                 const int* __restrict__ ecol,
                                                 const float* __restrict__ dinv,
                                                 const ushort_t* __restrict__ x,
                                                 ushort_t* __restrict__ y, int n_nodes) {
    int wave = blockIdx.x * (blockDim.x >> 6) + (threadIdx.x >> 6);
    if (wave >= n_nodes) return;
    int lane = threadIdx.x & 63;
    int g = lane >> 3;   // edge subgroup 0..7
    int l8 = lane & 7;   // dim-oct
    int start = offs[wave];
    int end = offs[wave + 1];
    f32x2 a0 = 0.f, a1 = 0.f, a2 = 0.f, a3 = 0.f;
    for (int base = start; base < end; base += 64) {
        int m = end - base;
        if (m > 64) m = 64;
        int il = base + lane;
        int c_lane = (il < end) ? ecol[il] : n_nodes;  // pad lanes -> zero row
        int nk = (m + 7) >> 3;
#pragma unroll 4
        for (int k = 0; k < nk; ++k) {
            int c = __shfl(c_lane, (k << 3) + g);  // register broadcast
            uint4 q = *(const uint4*)(x + ((size_t)c << 6) + l8 * 8);
            a0 += (f32x2){__uint_as_float(q.x << 16), __uint_as_float(q.x & 0xFFFF0000u)};
            a1 += (f32x2){__uint_as_float(q.y << 16), __uint_as_float(q.y & 0xFFFF0000u)};
            a2 += (f32x2){__uint_as_float(q.z << 16), __uint_as_float(q.z & 0xFFFF0000u)};
            a3 += (f32x2){__uint_as_float(q.w << 16), __uint_as_float(q.w & 0xFFFF0000u)};
        }
    }
    float r0 = a0.x, r1 = a0.y, r2 = a1.x, r3 = a1.y;
    float r4 = a2.x, r5 = a2.y, r6 = a3.x, r7 = a3.y;
#pragma unroll
    for (int msk = 8; msk <= 32; msk <<= 1) {
        r0 += __shfl_xor(r0, msk);
        r1 += __shfl_xor(r1, msk);
        r2 += __shfl_xor(r2, msk);
        r3 += __shfl_xor(r3, msk);
        r4 += __shfl_xor(r4, msk);
        r5 += __shfl_xor(r5, msk);
        r6 += __shfl_xor(r6, msk);
        r7 += __shfl_xor(r7, msk);
    }
    if (g == 0) {
        float dr = dinv[wave];
        float s = dr * dr;
        uint4 o;
        o.x = (unsigned)f2bf(s * r0) | ((unsigned)f2bf(s * r1) << 16);
        o.y = (unsigned)f2bf(s * r2) | ((unsigned)f2bf(s * r3) << 16);
        o.z = (unsigned)f2bf(s * r4) | ((unsigned)f2bf(s * r5) << 16);
        o.w = (unsigned)f2bf(s * r6) | ((unsigned)f2bf(s * r7) << 16);
        *(uint4*)(y + (size_t)wave * EMBED + l8 * 8) = o;
    }
}

// Single fused gather: out = 0.25*(e0_exact + sqrt(deg)*(L1+L2+L3)).
__global__ void gather_all(const float* __restrict__ ue, const float* __restrict__ ie,
                           const ushort_t* __restrict__ l1, const ushort_t* __restrict__ l2,
                           const ushort_t* __restrict__ l3, const int* __restrict__ deg,
                           const int* __restrict__ users, const int* __restrict__ pos,
                           const int* __restrict__ neg, float* __restrict__ out,
                           int batch, int n_users) {
    int idx = blockIdx.x * blockDim.x + threadIdx.x;
    int total = 3 * batch * EMBED;
    if (idx >= total) return;
    int r = idx >> 6;
    int d = idx & 63;
    int which = r / batch;
    int b = r - which * batch;
    int node;
    float e0;
    if (which == 0) {
        int u = users[b];
        node = u;
        e0 = ue[(size_t)u * EMBED + d];
    } else {
        int it = (which == 1) ? pos[b] : neg[b];
        node = n_users + it;
        e0 = ie[(size_t)it * EMBED + d];
    }
    float sd = sqrtf((float)max(deg[node], 1));
    size_t off = (size_t)node * EMBED + d;
    float s = bf2f(l1[off]) + bf2f(l2[off]) + bf2f(l3[off]);
    out[idx] = 0.25f * (e0 + sd * s);
}

extern "C" void kernel_launch(void* const* d_in, const int* in_sizes, int n_in,
                              void* d_out, int out_size, void* d_ws, size_t ws_size,
                              hipStream_t stream) {
    const float* user_emb = (const float*)d_in[0];
    const float* item_emb = (const float*)d_in[1];
    const int* row = (const int*)d_in[2];
    const int* col = (const int*)d_in[3];
    const int* users = (const int*)d_in[5];
    const int* pos = (const int*)d_in[6];
    const int* neg = (const int*)d_in[7];
    float* out = (float*)d_out;

    int n_users = in_sizes[0] / EMBED;
    int n_items = in_sizes[1] / EMBED;
    int n_nodes = n_users + n_items;
    int nnz = in_sizes[2];
    int batch = in_sizes[5];
    int nb = (n_nodes + BROWS - 1) / BROWS;   // 293
    int n2 = nb * NGROUPS;                    // 75008
    int epb = (nnz + NGROUPS - 1) / NGROUPS;  // 12500

    char* p = (char*)d_ws;
    auto alloc = [&](size_t bytes) -> void* {
        void* r = (void*)p;
        p += (bytes + 255) & ~(size_t)255;
        return r;
    };
    int ntiles1 = (n_nodes + SCAN_TILE - 1) / SCAN_TILE;
    int ntiles2 = (n2 + SCAN_TILE - 1) / SCAN_TILE;
    int ntiles_max = ntiles1 > ntiles2 ? ntiles1 : ntiles2;
    int* deg = (int*)alloc(sizeof(int) * (size_t)n_nodes);
    int* offs = (int*)alloc(sizeof(int) * (size_t)(n_nodes + 1));
    float* dinv = (float*)alloc(sizeof(float) * (size_t)n_nodes);
    int* cnt = (int*)alloc(sizeof(int) * (size_t)n2);
    int* cbase = (int*)alloc(sizeof(int) * (size_t)(n2 + 1));
    int* tile_sums = (int*)alloc(sizeof(int) * (size_t)ntiles_max);
    int* ecol = (int*)alloc(sizeof(int) * (size_t)nnz);
    ushort_t* bufA = (ushort_t*)alloc(sizeof(ushort_t) * (size_t)(n_nodes + 1) * EMBED);
    ushort_t* bufB = (ushort_t*)alloc(sizeof(ushort_t) * (size_t)(n_nodes + 1) * EMBED);
    ushort_t* bufC = (ushort_t*)alloc(sizeof(ushort_t) * (size_t)(n_nodes + 1) * EMBED);
    if ((size_t)(p - (char*)d_ws) > ws_size) return;  // workspace too small: bail visibly
    // tpack (12.8MB) aliases bufB (19.2MB): consumed by deg_dinv_x0 + pass2, both
    // of which run BEFORE the first spmm writes bufB. deg_dinv_x0 writes x0 into
    // bufA only; bufB's pad row (offset 19.2MB) is beyond tpack's 12.8MB.
    int* tpack = (int*)bufB;

    passA_hist<<<NGROUPS, 256, 0, stream>>>(row, cnt, nnz, nb, epb);
    scan_tiles<<<ntiles2, SCAN_THREADS, 0, stream>>>(cnt, cbase, tile_sums, n2);
    add_bases_f<<<(n2 + 256) / 256, 256, 0, stream>>>(cbase, tile_sums, n2, ntiles2);
    passB_scatter<<<NGROUPS, 256, 0, stream>>>(row, col, cbase, tpack, nnz, nb, epb);

    deg_dinv_x0<<<nb, 256, 0, stream>>>(cbase, tpack, user_emb, item_emb, deg, dinv,
                                        bufA, bufB, bufC, n_nodes, n_users);
    scan_tiles<<<ntiles1, SCAN_THREADS, 0, stream>>>(deg, offs, tile_sums, n_nodes);
    add_bases_f<<<(n_nodes + 256) / 256, 256, 0, stream>>>(offs, tile_sums, n_nodes, ntiles1);
    pass2_place<<<nb, 256, 0, stream>>>(offs, tpack, ecol, n_nodes);

    int spmm_blocks = (n_nodes + 3) / 4;
    spmm_bf16<<<spmm_blocks, 256, 0, stream>>>(offs, ecol, dinv, bufA, bufB, n_nodes);  // L1
    spmm_bf16<<<spmm_blocks, 256, 0, stream>>>(offs, ecol, dinv, bufB, bufC, n_nodes);  // L2
    spmm_bf16<<<spmm_blocks, 256, 0, stream>>>(offs, ecol, dinv, bufC, bufA, n_nodes);  // L3

    int gblocks = (3 * batch * EMBED + 255) / 256;
    gather_all<<<gblocks, 256, 0, stream>>>(user_emb, item_emb, bufB, bufC, bufA, deg,
                                            users, pos, neg, out, batch, n_users);
}

// Round 9
// 292.733 us; speedup vs baseline: 1.8329x; 1.1493x over previous
//
#include <hip/hip_runtime.h>

#define EMBED 64
#define BSHIFT 9
#define BROWS 512      // rows per coarse bucket
#define NGROUPS 256    // passA/passB write-front groups (private fronts)
#define PTHREADS 1024  // threads for the 4 big preprocessing kernels
#define MAXNB 512      // max buckets supported by LDS arrays (nb=293 here)
#define SCAN_THREADS 256
#define SCAN_ITEMS 16
#define SCAN_TILE (SCAN_THREADS * SCAN_ITEMS)  // 4096
// tpack: (row & 511) << 20 | col   (col < 2^20; n_nodes = 150K fits)
// ecol: BYTE offset col<<7 (row stride 128 B); pad row = n_nodes<<7

typedef unsigned short ushort_t;
typedef __attribute__((ext_vector_type(2))) float f32x2;

__device__ __forceinline__ ushort_t f2bf(float f) {  // RTNE
    unsigned u = __float_as_uint(f);
    return (ushort_t)((u + 0x7FFFu + ((u >> 16) & 1u)) >> 16);
}
__device__ __forceinline__ float bf2f(ushort_t b) {
    return __uint_as_float(((unsigned)b) << 16);
}

// Generic per-tile exclusive scan: in -> out (tile-local) + tile sums.
__global__ void scan_tiles(const int* __restrict__ in, int* __restrict__ out,
                           int* __restrict__ tile_sums, int n) {
    __shared__ int sh[SCAN_THREADS];
    int t = threadIdx.x;
    int base = blockIdx.x * SCAN_TILE + t * SCAN_ITEMS;
    int vals[SCAN_ITEMS];
    int sum = 0;
#pragma unroll
    for (int k = 0; k < SCAN_ITEMS; ++k) {
        int idx = base + k;
        vals[k] = (idx < n) ? in[idx] : 0;
        sum += vals[k];
    }
    sh[t] = sum;
    __syncthreads();
    for (int off = 1; off < SCAN_THREADS; off <<= 1) {
        int v = (t >= off) ? sh[t - off] : 0;
        __syncthreads();
        sh[t] += v;
        __syncthreads();
    }
    int excl = sh[t] - sum;
    if (t == SCAN_THREADS - 1) tile_sums[blockIdx.x] = sh[t];
    int run = excl;
#pragma unroll
    for (int k = 0; k < SCAN_ITEMS; ++k) {
        int idx = base + k;
        if (idx < n) out[idx] = run;
        run += vals[k];
    }
}

// Folded scan_bases+add_bases: each thread re-sums the (<=37) tile sums.
__global__ void add_bases_f(int* __restrict__ arr, const int* __restrict__ tile_sums,
                            int n, int ntiles) {
    int i = blockIdx.x * blockDim.x + threadIdx.x;
    if (i >= n) {
        if (i == n) {
            int s = 0;
            for (int j = 0; j < ntiles; ++j) s += tile_sums[j];
            arr[n] = s;
        }
        return;
    }
    int myt = i / SCAN_TILE;
    int base = 0;
    for (int j = 0; j < myt; ++j) base += tile_sums[j];
    arr[i] += base;
}

// passA: per-group LDS histogram over coarse buckets -> cnt[bucket][group].
__global__ __launch_bounds__(PTHREADS) void passA_hist(const int* __restrict__ row,
                                                       int* __restrict__ cnt,
                                                       int nnz, int nb, int epb) {
    __shared__ int hist[MAXNB];
    int g = blockIdx.x, t = threadIdx.x;
    for (int b = t; b < nb; b += PTHREADS) hist[b] = 0;
    __syncthreads();
    int i0 = g * epb, i1 = min(i0 + epb, nnz);
    for (int i = i0 + t; i < i1; i += PTHREADS) atomicAdd(&hist[row[i] >> BSHIFT], 1);
    __syncthreads();
    for (int b = t; b < nb; b += PTHREADS) cnt[b * NGROUPS + g] = hist[b];
}

// passB: deterministic scatter into group-private dense fronts (LDS cursors,
// no global atomics). 4 B/edge: (rlocal<<20)|col.
__global__ __launch_bounds__(PTHREADS) void passB_scatter(const int* __restrict__ row,
                                                          const int* __restrict__ col,
                                                          const int* __restrict__ cbase,
                                                          int* __restrict__ tpack,
                                                          int nnz, int nb, int epb) {
    __shared__ int lcur[MAXNB];
    int g = blockIdx.x, t = threadIdx.x;
    for (int b = t; b < nb; b += PTHREADS) lcur[b] = cbase[b * NGROUPS + g];
    __syncthreads();
    int i0 = g * epb, i1 = min(i0 + epb, nnz);
    for (int i = i0 + t; i < i1; i += PTHREADS) {
        int r = row[i];
        int slot = atomicAdd(&lcur[r >> BSHIFT], 1);
        tpack[slot] = ((r & (BROWS - 1)) << 20) | col[i];
    }
}

// Fused: deg (LDS histogram over bucket-grouped tpack) + dinv + pre-scaled
// bf16 x0 rows for this bucket + zero pad rows (block 0).
__global__ __launch_bounds__(PTHREADS) void deg_dinv_x0(const int* __restrict__ cbase,
                                                        const int* __restrict__ tpack,
                                                        const float* __restrict__ ue,
                                                        const float* __restrict__ ie,
                                                        int* __restrict__ deg,
                                                        float* __restrict__ dinv,
                                                        ushort_t* __restrict__ xa,
                                                        ushort_t* __restrict__ xb,
                                                        ushort_t* __restrict__ xc,
                                                        int n_nodes, int n_users) {
    __shared__ int hist[BROWS];
    __shared__ float sdinv[BROWS];
    int b = blockIdx.x, t = threadIdx.x;
    int r0 = b * BROWS;
    int r1 = min(r0 + BROWS, n_nodes);
    for (int r = t; r < BROWS; r += PTHREADS) hist[r] = 0;
    __syncthreads();
    int es = cbase[b * NGROUPS];
    int ee = cbase[(b + 1) * NGROUPS];  // cbase[n2] == nnz
    for (int e = es + t; e < ee; e += PTHREADS) atomicAdd(&hist[((unsigned)tpack[e]) >> 20], 1);
    __syncthreads();
    for (int r = t; r < r1 - r0; r += PTHREADS) {
        int d = hist[r];
        deg[r0 + r] = d;
        float di = 1.0f / sqrtf((float)max(d, 1));
        dinv[r0 + r] = di;
        sdinv[r] = di;
    }
    __syncthreads();
    int nq = (r1 - r0) * 16;  // ushort4 quads in this bucket
    for (int idx = t; idx < nq; idx += PTHREADS) {
        int rl = idx >> 4, q = idx & 15;
        int grow = r0 + rl;
        const float* src = (grow < n_users) ? (ue + (size_t)grow * EMBED)
                                            : (ie + (size_t)(grow - n_users) * EMBED);
        float4 v = ((const float4*)src)[q];
        float d = sdinv[rl];
        ushort4 o;
        o.x = f2bf(d * v.x); o.y = f2bf(d * v.y); o.z = f2bf(d * v.z); o.w = f2bf(d * v.w);
        ((ushort4*)(xa + (size_t)grow * EMBED))[q] = o;
    }
    if (b == 0 && t < 48) {  // zero the pad row (index n_nodes) of all 3 buffers
        ushort4 z = {0, 0, 0, 0};
        ushort_t* tgt = (t < 16) ? xa : ((t < 32) ? xb : xc);
        ((ushort4*)(tgt + (size_t)n_nodes * EMBED))[t & 15] = z;
    }
}

// pass2: one block per bucket; LDS row-cursors; CSR writes confined to the
// bucket's contiguous span (L2-resident). Stores BYTE offsets col<<7.
__global__ __launch_bounds__(PTHREADS) void pass2_place(const int* __restrict__ offs,
                                                        const int* __restrict__ tpack,
                                                        int* __restrict__ eoff, int n_nodes) {
    __shared__ int lcur[BROWS];
    int b = blockIdx.x;
    int t = threadIdx.x;
    int r0 = b * BROWS;
    int r1 = min(r0 + BROWS, n_nodes);
    if (r0 >= n_nodes) return;
    for (int r = t; r < r1 - r0; r += PTHREADS) lcur[r] = offs[r0 + r];
    __syncthreads();
    int es = offs[r0];
    int ee = offs[r1];
    for (int e = es + t; e < ee; e += PTHREADS) {
        int pk = tpack[e];
        int slot = atomicAdd(&lcur[((unsigned)pk) >> 20], 1);
        eoff[slot] = (pk & 0xFFFFF) << 7;
    }
}

// SPMM on pre-scaled embeddings: acc_r = sum x~[c]; write x~_next = dinv[r]^2 * acc.
// 8 edge-groups x 8 lanes x uint4 (8 bf16). Per 64-edge chunk: one coalesced
// eoff load; wave-uniform Duff switch -> straight-line shfl+gather code with up
// to 8 independent gathers in flight; pad lanes hit the zero row (L1-hot).
__global__ __launch_bounds__(256, 8) void spmm_bf16(const int* __restrict__ offs,
                                                    const int* __restrict__ eoff,
                                                    const float* __restrict__ dinv,
                                                    const ushort_t* __restrict__ x,
                                                    ushort_t* __restrict__ y, int n_nodes) {
    int wave = blockIdx.x * (blockDim.x >> 6) + (threadIdx.x >> 6);
    if (wave >= n_nodes) return;
    int lane = threadIdx.x & 63;
    int g = lane >> 3;   // edge subgroup 0..7
    int l8 = lane & 7;   // dim-oct
    int start = offs[wave];
    int end = offs[wave + 1];
    int pad = n_nodes << 7;
    const char* xb = (const char*)x + (l8 << 4);  // per-lane 16B slice base
    f32x2 a0 = 0.f, a1 = 0.f, a2 = 0.f, a3 = 0.f;
#define GATH(K)                                                                           \
    {                                                                                     \
        int cc = __shfl(c_lane, (K << 3) + g);                                            \
        uint4 q = *(const uint4*)(xb + cc);                                               \
        a0 += (f32x2){__uint_as_float(q.x << 16), __uint_as_float(q.x & 0xFFFF0000u)};    \
        a1 += (f32x2){__uint_as_float(q.y << 16), __uint_as_float(q.y & 0xFFFF0000u)};    \
        a2 += (f32x2){__uint_as_float(q.z << 16), __uint_as_float(q.z & 0xFFFF0000u)};    \
        a3 += (f32x2){__uint_as_float(q.w << 16), __uint_as_float(q.w & 0xFFFF0000u)};    \
    }
    for (int base = start; base < end; base += 64) {
        int m = end - base;
        if (m > 64) m = 64;
        int il = base + lane;
        int c_lane = (il < end) ? eoff[il] : pad;  // pad lanes -> zero row
        int nk = (m + 7) >> 3;                     // wave-uniform
        switch (nk) {
            case 8: GATH(7); [[fallthrough]];
            case 7: GATH(6); [[fallthrough]];
            case 6: GATH(5); [[fallthrough]];
            case 5: GATH(4); [[fallthrough]];
            case 4: GATH(3); [[fallthrough]];
            case 3: GATH(2); [[fallthrough]];
            case 2: GATH(1); [[fallthrough]];
            case 1: GATH(0);
        }
    }
#undef GATH
    float r0 = a0.x, r1 = a0.y, r2 = a1.x, r3 = a1.y;
    float r4 = a2.x, r5 = a2.y, r6 = a3.x, r7 = a3.y;
#pragma unroll
    for (int msk = 8; msk <= 32; msk <<= 1) {
        r0 += __shfl_xor(r0, msk);
        r1 += __shfl_xor(r1, msk);
        r2 += __shfl_xor(r2, msk);
        r3 += __shfl_xor(r3, msk);
        r4 += __shfl_xor(r4, msk);
        r5 += __shfl_xor(r5, msk);
        r6 += __shfl_xor(r6, msk);
        r7 += __shfl_xor(r7, msk);
    }
    if (g == 0) {
        float dr = dinv[wave];
        float s = dr * dr;
        uint4 o;
        o.x = (unsigned)f2bf(s * r0) | ((unsigned)f2bf(s * r1) << 16);
        o.y = (unsigned)f2bf(s * r2) | ((unsigned)f2bf(s * r3) << 16);
        o.z = (unsigned)f2bf(s * r4) | ((unsigned)f2bf(s * r5) << 16);
        o.w = (unsigned)f2bf(s * r6) | ((unsigned)f2bf(s * r7) << 16);
        *(uint4*)(y + (size_t)wave * EMBED + l8 * 8) = o;
    }
}

// Single fused gather: out = 0.25*(e0_exact + sqrt(deg)*(L1+L2+L3)).
__global__ void gather_all(const float* __restrict__ ue, const float* __restrict__ ie,
                           const ushort_t* __restrict__ l1, const ushort_t* __restrict__ l2,
                           const ushort_t* __restrict__ l3, const int* __restrict__ deg,
                           const int* __restrict__ users, const int* __restrict__ pos,
                           const int* __restrict__ neg, float* __restrict__ out,
                           int batch, int n_users) {
    int idx = blockIdx.x * blockDim.x + threadIdx.x;
    int total = 3 * batch * EMBED;
    if (idx >= total) return;
    int r = idx >> 6;
    int d = idx & 63;
    int which = r / batch;
    int b = r - which * batch;
    int node;
    float e0;
    if (which == 0) {
        int u = users[b];
        node = u;
        e0 = ue[(size_t)u * EMBED + d];
    } else {
        int it = (which == 1) ? pos[b] : neg[b];
        node = n_users + it;
        e0 = ie[(size_t)it * EMBED + d];
    }
    float sd = sqrtf((float)max(deg[node], 1));
    size_t off = (size_t)node * EMBED + d;
    float s = bf2f(l1[off]) + bf2f(l2[off]) + bf2f(l3[off]);
    out[idx] = 0.25f * (e0 + sd * s);
}

extern "C" void kernel_launch(void* const* d_in, const int* in_sizes, int n_in,
                              void* d_out, int out_size, void* d_ws, size_t ws_size,
                              hipStream_t stream) {
    const float* user_emb = (const float*)d_in[0];
    const float* item_emb = (const float*)d_in[1];
    const int* row = (const int*)d_in[2];
    const int* col = (const int*)d_in[3];
    const int* users = (const int*)d_in[5];
    const int* pos = (const int*)d_in[6];
    const int* neg = (const int*)d_in[7];
    float* out = (float*)d_out;

    int n_users = in_sizes[0] / EMBED;
    int n_items = in_sizes[1] / EMBED;
    int n_nodes = n_users + n_items;
    int nnz = in_sizes[2];
    int batch = in_sizes[5];
    int nb = (n_nodes + BROWS - 1) / BROWS;   // 293
    int n2 = nb * NGROUPS;                    // 75008
    int epb = (nnz + NGROUPS - 1) / NGROUPS;  // 12500

    char* p = (char*)d_ws;
    auto alloc = [&](size_t bytes) -> void* {
        void* r = (void*)p;
        p += (bytes + 255) & ~(size_t)255;
        return r;
    };
    int ntiles1 = (n_nodes + SCAN_TILE - 1) / SCAN_TILE;
    int ntiles2 = (n2 + SCAN_TILE - 1) / SCAN_TILE;
    int ntiles_max = ntiles1 > ntiles2 ? ntiles1 : ntiles2;
    int* deg = (int*)alloc(sizeof(int) * (size_t)n_nodes);
    int* offs = (int*)alloc(sizeof(int) * (size_t)(n_nodes + 1));
    float* dinv = (float*)alloc(sizeof(float) * (size_t)n_nodes);
    int* cnt = (int*)alloc(sizeof(int) * (size_t)n2);
    int* cbase = (int*)alloc(sizeof(int) * (size_t)(n2 + 1));
    int* tile_sums = (int*)alloc(sizeof(int) * (size_t)ntiles_max);
    int* eoff = (int*)alloc(sizeof(int) * ((size_t)nnz + 64));  // +64: Duff tail reads
    ushort_t* bufA = (ushort_t*)alloc(sizeof(ushort_t) * (size_t)(n_nodes + 1) * EMBED);
    ushort_t* bufB = (ushort_t*)alloc(sizeof(ushort_t) * (size_t)(n_nodes + 1) * EMBED);
    ushort_t* bufC = (ushort_t*)alloc(sizeof(ushort_t) * (size_t)(n_nodes + 1) * EMBED);
    if ((size_t)(p - (char*)d_ws) > ws_size) return;  // workspace too small: bail visibly
    // tpack (12.8MB) aliases bufB (19.2MB): consumed by deg_dinv_x0 + pass2, both
    // of which run BEFORE the first spmm writes bufB. deg_dinv_x0 writes x0 into
    // bufA only; bufB's pad row (offset 19.2MB) is beyond tpack's 12.8MB.
    int* tpack = (int*)bufB;

    passA_hist<<<NGROUPS, PTHREADS, 0, stream>>>(row, cnt, nnz, nb, epb);
    scan_tiles<<<ntiles2, SCAN_THREADS, 0, stream>>>(cnt, cbase, tile_sums, n2);
    add_bases_f<<<(n2 + 256) / 256, 256, 0, stream>>>(cbase, tile_sums, n2, ntiles2);
    passB_scatter<<<NGROUPS, PTHREADS, 0, stream>>>(row, col, cbase, tpack, nnz, nb, epb);

    deg_dinv_x0<<<nb, PTHREADS, 0, stream>>>(cbase, tpack, user_emb, item_emb, deg, dinv,
                                             bufA, bufB, bufC, n_nodes, n_users);
    scan_tiles<<<ntiles1, SCAN_THREADS, 0, stream>>>(deg, offs, tile_sums, n_nodes);
    add_bases_f<<<(n_nodes + 256) / 256, 256, 0, stream>>>(offs, tile_sums, n_nodes, ntiles1);
    pass2_place<<<nb, PTHREADS, 0, stream>>>(offs, tpack, eoff, n_nodes);

    int spmm_blocks = (n_nodes + 3) / 4;
    spmm_bf16<<<spmm_blocks, 256, 0, stream>>>(offs, eoff, dinv, bufA, bufB, n_nodes);  // L1
    spmm_bf16<<<spmm_blocks, 256, 0, stream>>>(offs, eoff, dinv, bufB, bufC, n_nodes);  // L2
    spmm_bf16<<<spmm_blocks, 256, 0, stream>>>(offs, eoff, dinv, bufC, bufA, n_nodes);  // L3

    int gblocks = (3 * batch * EMBED + 255) / 256;
    gather_all<<<gblocks, 256, 0, stream>>>(user_emb, item_emb, bufB, bufC, bufA, deg,
                                            users, pos, neg, out, batch, n_users);
}